// Round 3
// baseline (149.048 us; speedup 1.0000x reference)
//
#include <hip/hip_runtime.h>
#include <hip/hip_bf16.h>

typedef short bf16x8 __attribute__((ext_vector_type(8)));
typedef float f32x16 __attribute__((ext_vector_type(16)));
typedef float f32x4  __attribute__((ext_vector_type(4)));
typedef float f32x2  __attribute__((ext_vector_type(2)));

#define NCOL  32
#define KS1   112             // f1 k-steps (K=1792, 16 per step, 4 s per step)
#define KS2   12              // f2 k-steps (K=192)
#define ESTR  528             // E row stride bytes (32 cols * 16B + 16 pad)

#define WP_OFF   0            // short [112][2][64][8] = 229376 B
#define W2P_OFF  229376       // short [12][2][64][8]  = 24576 B

#define MET_OFF  21648        // E region 41*528 = 21648; meta uint2[464] = 3712
#define SUM_OFF  25360        // f32 [128][32] = 16384 (single region, ds_add)
#define LDS_BYTES 41744

__device__ __forceinline__ unsigned short f2bf(float f) {
    union { float f; unsigned u; } v; v.f = f;
    unsigned r = v.u + 0x7FFFu + ((v.u >> 16) & 1u);
    return (unsigned short)(r >> 16);
}
__device__ __forceinline__ unsigned pk2(float a, float b) {
    __hip_bfloat162 h = __float22bfloat162_rn(make_float2(a, b));
    unsigned u; __builtin_memcpy(&u, &h, 4); return u;
}
__device__ __forceinline__ bf16x8 asbf(uint4 v) {
    union { uint4 u; bf16x8 b; } z; z.u = v; return z.b;
}
__device__ __forceinline__ f32x16 zero16() {
    f32x16 z;
#pragma unroll
    for (int i = 0; i < 16; ++i) z[i] = 0.f;
    return z;
}

// prep: A-frag layout for mfma_32x32x16 (validated mapping from prior session).
// Wp[ks][mt][lane][8 shorts]; row = mt*32 + (lane&31); k = ks*16+(lane>>5)*8+v.
// Rows 0..39 = W1 (o=row>>2, p=(row>>1)&1, reim=row&1); rows 40..43 = pbc C;
// rows 44..63 zero.
// k -> s=k>>2, t=k&3 (i=t&1 pol, cc=t>>1 re/im), plane j=i^p.
__global__ void prep_kernel(const float* __restrict__ W1,
                            const float* __restrict__ W2,
                            const float* __restrict__ pbcC,
                            unsigned short* __restrict__ Wp,
                            unsigned short* __restrict__ W2p, int S) {
    int idx = blockIdx.x * 256 + threadIdx.x;
    const int N1 = KS1 * 2 * 64 * 2;   // 28672
    const int N2 = KS2 * 2 * 64 * 2;   // 3072
    if (idx < N1) {
        int ks = idx >> 8, rem = idx & 255;
        int mt = rem >> 7; rem &= 127;
        int lane = rem >> 1, jh = rem & 1;
        int row = mt * 32 + (lane & 31);
        int kg  = ks * 16 + (lane >> 5) * 8 + jh * 4;
        int s   = kg >> 2;
        float2 wj0 = make_float2(0.f, 0.f), wj1 = make_float2(0.f, 0.f);
        int p = 0, r = 0;
        if (s < S) {
            if (row < 40) {
                int o = row >> 2; p = (row >> 1) & 1; r = row & 1;
                wj0 = ((const float2*)W1)[(size_t)(o * 2 + 0) * S + s];
                wj1 = ((const float2*)W1)[(size_t)(o * 2 + 1) * S + s];
            } else if (row < 44) {
                p = (row >> 1) & 1; r = row & 1;
                wj0 = ((const float2*)pbcC)[s];
            }
        }
        ushort4 h; unsigned short us[4];
#pragma unroll
        for (int t = 0; t < 4; ++t) {
            int i = t & 1, cc = t >> 1, j2 = i ^ p;
            float2 w = j2 ? wj1 : wj0;
            float v = (cc == 0) ? (r ? w.y : w.x) : (r ? w.x : -w.y);
            us[t] = f2bf(v);
        }
        h.x = us[0]; h.y = us[1]; h.z = us[2]; h.w = us[3];
        ((ushort4*)Wp)[idx] = h;
        return;
    }
    idx -= N1;
    if (idx < N2) {
        int ks = idx >> 8, rem = idx & 255;
        int mt = rem >> 7; rem &= 127;
        int lane = rem >> 1, jh = rem & 1;
        int row = mt * 32 + (lane & 31);
        int kg  = ks * 16 + (lane >> 5) * 8 + jh * 4;
        int m   = kg >> 2;
        float2 wj0 = make_float2(0.f, 0.f), wj1 = make_float2(0.f, 0.f);
        int p = 0, r = 0;
        if (m < 41 && row < 40) {
            int o = row >> 2; p = (row >> 1) & 1; r = row & 1;
            wj0 = ((const float2*)W2)[(o * 2 + 0) * 41 + m];
            wj1 = ((const float2*)W2)[(o * 2 + 1) * 41 + m];
        }
        ushort4 h; unsigned short us[4];
#pragma unroll
        for (int t = 0; t < 4; ++t) {
            int i = t & 1, cc = t >> 1, j2 = i ^ p;
            float2 w = j2 ? wj1 : wj0;
            float v = (cc == 0) ? (r ? w.y : w.x) : (r ? w.x : -w.y);
            us[t] = f2bf(v);
        }
        h.x = us[0]; h.y = us[1]; h.z = us[2]; h.w = us[3];
        ((ushort4*)W2p)[idx] = h;
    }
}

// 512-thr blocks: 32 cols, 8 waves = K-eighths (14 ks each) -> 4 waves/SIMD.
// E staged in LDS as fp32, re/im-split packed (r0,r1,i0,i1); complex math as
// packed f32x2 (v_pk_fma). A-frags prefetched 2 ks ahead (L2 latency cover).
// Reduction via ds_add_f32 (atomicAdd on LDS): one Sum region, no phases,
// f1 accs dumped before f2 so the atomics hide under f2's MFMA work.
// Only 2 __syncthreads in the whole kernel.
__global__ __launch_bounds__(512, 4) void eqsonn_kernel(
    const float* __restrict__ x, const float* __restrict__ task,
    const unsigned short* __restrict__ Wp,  // short [112][2][64][8]
    const unsigned short* __restrict__ W2p, // short [12][2][64][8]
    const int* __restrict__ m_idx, const int* __restrict__ n_idx,
    const float* __restrict__ b1, const float* __restrict__ b2,
    float* __restrict__ out, int B, int S)
{
    __shared__ alignas(16) char ldsb[LDS_BYTES];
    const int tid  = threadIdx.x;
    const int lane = tid & 63;
    const int w    = __builtin_amdgcn_readfirstlane(tid >> 6);   // 0..7
    const int col  = lane & 31;
    const int kha  = lane >> 5;
    const int b0   = blockIdx.x * NCOL;
    float* SumF = (float*)(ldsb + SUM_OFF);

    // ---- stage E fp32: row k at k*528 + col*16, permuted to (r0,r1,i0,i1) ----
    for (int e = tid; e < 41 * NCOL; e += 512) {
        int bb = e / 41, k = e - bb * 41;
        int bs = b0 + bb; if (bs > B - 1) bs = B - 1;
        float4 v = ((const float4*)x)[(size_t)bs * 41 + k];
        f32x4 pv; pv.x = v.x; pv.y = v.z; pv.z = v.y; pv.w = v.w;
        *(f32x4*)(ldsb + k * ESTR + bb * 16) = pv;
    }
    // ---- zero Sum region (1024 float4) ----
    {
        float4 z4 = make_float4(0.f, 0.f, 0.f, 0.f);
        float4* Z = (float4*)(ldsb + SUM_OFF);
        Z[tid] = z4; Z[tid + 512] = z4;
    }
    // ---- stage meta byte-offsets, zero-padded to 464 ----
    if (tid < 464) {
        int m = 0, n = 0;
        if (tid < S) { m = m_idx[tid]; n = n_idx[tid]; }
        unsigned offM = (unsigned)((20 + m) * ESTR);
        unsigned offB = (unsigned)((20 + m + n) * ESTR);
        unsigned offN = (unsigned)((20 + n) * ESTR);
        *(uint2*)(ldsb + MET_OFF + tid * 8) = make_uint2(offM | (offB << 16), offN);
    }
    __syncthreads();

    const char* Ebase = ldsb + col * 16;
    auto ldM4 = [&](int ks) -> uint4 {
        return *(const uint4*)(ldsb + MET_OFF + (ks * 4 + kha * 2) * 8);
    };
    auto ldE = [&](unsigned off) -> f32x4 {
        return *(const f32x4*)(Ebase + off);
    };
    // em/eq/en = (r0, r1, i0, i1); A = sum_p E_m[p]*conj(E_q[p]); F[p]=A*E_n[p]
    auto fbuild = [&](f32x4 em, f32x4 eq, f32x4 en, unsigned& lo, unsigned& hi) {
        f32x2 mr = em.xy, mi = em.zw;
        f32x2 qr = eq.xy, qi = eq.zw;
        f32x2 nr = en.xy, ni = en.zw;
        f32x2 t = mr * qr + mi * qi;       // Re per-pol
        f32x2 u = mi * qr - mr * qi;       // Im per-pol
        float sr = t.x + t.y, si = u.x + u.y;
        f32x2 Fr = sr * nr - si * ni;
        f32x2 Fi = sr * ni + si * nr;
        lo = pk2(Fr.x, Fr.y); hi = pk2(Fi.x, Fi.y);
    };

    // ---- f1 K-loop: 14 ksteps/wave, pipelined, barrier-free ----
    f32x16 ac0 = zero16(), ac1 = zero16();
    {
        const int ks0 = w * 14;
        const short* Wp16 = (const short*)Wp;
        uint4 M = ldM4(ks0);
        f32x4 e0 = ldE(M.x & 0xffffu), e1 = ldE(M.x >> 16), e2 = ldE(M.y);
        f32x4 e3 = ldE(M.z & 0xffffu), e4 = ldE(M.z >> 16), e5 = ldE(M.w);
        uint4 Mc = ldM4(ks0 + 1);
        const short* ap0 = Wp16 + (size_t)ks0 * 1024 + lane * 8;
        bf16x8 A0 = *(const bf16x8*)(ap0);
        bf16x8 A1 = *(const bf16x8*)(ap0 + 512);
        const short* ap1 = Wp16 + (size_t)(ks0 + 1) * 1024 + lane * 8;
        bf16x8 B0 = *(const bf16x8*)(ap1);
        bf16x8 B1 = *(const bf16x8*)(ap1 + 512);
        for (int ks = ks0; ks < ks0 + 14; ++ks) {
            // prefetch A-frags 2 ahead (wave-uniform clamp; covers L2 latency)
            int ksn = (ks + 2 < KS1) ? ks + 2 : KS1 - 1;
            const short* apn = Wp16 + (size_t)ksn * 1024 + lane * 8;
            bf16x8 C0 = *(const bf16x8*)(apn);
            bf16x8 C1 = *(const bf16x8*)(apn + 512);
            // prefetch next E values + meta 2 ahead
            f32x4 f0 = ldE(Mc.x & 0xffffu), f1v = ldE(Mc.x >> 16), f2v = ldE(Mc.y);
            f32x4 f3 = ldE(Mc.z & 0xffffu), f4v = ldE(Mc.z >> 16), f5v = ldE(Mc.w);
            uint4 Mn = ldM4(ks + 2);
            unsigned g0, g1, g2, g3;
            fbuild(e0, e1, e2, g0, g1);
            fbuild(e3, e4, e5, g2, g3);
            bf16x8 bfr = asbf(make_uint4(g0, g1, g2, g3));
            ac0 = __builtin_amdgcn_mfma_f32_32x32x16_bf16(A0, bfr, ac0, 0, 0, 0);
            ac1 = __builtin_amdgcn_mfma_f32_32x32x16_bf16(A1, bfr, ac1, 0, 0, 0);
            e0 = f0; e1 = f1v; e2 = f2v; e3 = f3; e4 = f4v; e5 = f5v; Mc = Mn;
            A0 = B0; A1 = B1; B0 = C0; B1 = C1;
        }
    }

    // ---- dump f1 accs via LDS atomics (hide under f2); skip zero rows ----
    // ac0 rows 0..31 (16 regs), ac1 rows 32..47 (regs 0..7; 8..15 are zero).
    auto dumpat = [&](f32x16 a, int baserow, int nregs) {
#pragma unroll
        for (int reg = 0; reg < 16; ++reg) {
            if (reg >= nregs) break;
            int row = baserow + (reg & 3) + 8 * (reg >> 2) + 4 * kha;
            atomicAdd(&SumF[row * 32 + col], a[reg]);
        }
    };
    dumpat(ac0, 0, 16);
    dumpat(ac1, 32, 8);

    // ---- f2 (E region immutable; m>=41 B-garbage killed by zero A-frags) ----
    f32x16 bc0 = zero16(), bc1 = zero16();
    {
        const short* W216 = (const short*)W2p;
        for (int ks2 = w; ks2 < KS2; ks2 += 8) {
            const short* ap = W216 + (size_t)ks2 * 1024 + lane * 8;
            bf16x8 A0 = *(const bf16x8*)(ap);
            bf16x8 A1 = *(const bf16x8*)(ap + 512);
            unsigned g[4];
#pragma unroll
            for (int j = 0; j < 2; ++j) {
                int m = ks2 * 4 + kha * 2 + j;   // up to 47: rows 41..47 read
                f32x4 v = *(const f32x4*)(ldsb + m * ESTR + col * 16);  // meta pad, finite
                g[j * 2]     = pk2(v.x, v.y);   // (E0r, E1r)
                g[j * 2 + 1] = pk2(v.z, v.w);   // (E0i, E1i)
            }
            bf16x8 bfr = asbf(make_uint4(g[0], g[1], g[2], g[3]));
            bc0 = __builtin_amdgcn_mfma_f32_32x32x16_bf16(A0, bfr, bc0, 0, 0, 0);
            bc1 = __builtin_amdgcn_mfma_f32_32x32x16_bf16(A1, bfr, bc1, 0, 0, 0);
        }
    }
    // bc0 rows 64..95 (16 regs), bc1 rows 96..103 (regs 0..3; rest zero).
    dumpat(bc0, 64, 16);
    dumpat(bc1, 96, 4);
    __syncthreads();

    // ---- epilogue: wave 0, lanes 0..31 ----
    if (w == 0 && lane < NCOL) {
        const float* Sum = SumF;
        int c = lane;
        float pr0 = Sum[40 * 32 + c], pi0 = Sum[41 * 32 + c];
        float pr1 = Sum[42 * 32 + c], pi1 = Sum[43 * 32 + c];
        float t0 = 0.f, t1 = 0.f, t2 = 0.f, t3 = 0.f;
#pragma unroll
        for (int o = 0; o < 10; ++o) {
            float b2r = b2[o * 2], b2i = b2[o * 2 + 1];
            float b1r = b1[o * 2], b1i = b1[o * 2 + 1];
            int rb = o * 4;
            float B0r = Sum[(64 + rb + 0) * 32 + c] + b2r;
            float B0i = Sum[(64 + rb + 1) * 32 + c] + b2i;
            float B1r = Sum[(64 + rb + 2) * 32 + c] + b2r;
            float B1i = Sum[(64 + rb + 3) * 32 + c] + b2i;
            float A0r = Sum[(rb + 0) * 32 + c] + b1r;
            float A0i = Sum[(rb + 1) * 32 + c] + b1i;
            float A1r = Sum[(rb + 2) * 32 + c] + b1r;
            float A1i = Sum[(rb + 3) * 32 + c] + b1i;
            // A*B*conj(B) + conj(A)*B*B = 2*Re(A*conj(B)) * B
            float g0 = 2.f * (A0r * B0r + A0i * B0i);
            t0 += g0 * B0r; t1 += g0 * B0i;
            float g1 = 2.f * (A1r * B1r + A1i * B1i);
            t2 += g1 * B1r; t3 += g1 * B1i;
        }
        int b = b0 + c;
        if (b < B) {
            float dbm = task[(size_t)b * 4];
            float P   = exp2f(dbm * 0.33219280948873623f) * 0.5f;  // 10^(dbm/10)/2
            float kP2 = 3.1622776601683794e-05f * P * P;           // 1e-4/sqrt(10)*P^2
            float4 Ec = ((const float4*)x)[(size_t)b * 41 + 20];   // fp32 center
            float4 o4;
            o4.x = Ec.x + P * pr0 + kP2 * t0;
            o4.y = Ec.y + P * pi0 + kP2 * t1;
            o4.z = Ec.z + P * pr1 + kP2 * t2;
            o4.w = Ec.w + P * pi1 + kP2 * t3;
            ((float4*)out)[b] = o4;
        }
    }
}

extern "C" void kernel_launch(void* const* d_in, const int* in_sizes, int n_in,
                              void* d_out, int out_size, void* d_ws, size_t ws_size,
                              hipStream_t stream) {
    const float* x     = (const float*)d_in[0];
    const float* task  = (const float*)d_in[1];
    const float* pbcC  = (const float*)d_in[2];
    const float* W1    = (const float*)d_in[3];
    const float* b1    = (const float*)d_in[4];
    const float* W2    = (const float*)d_in[5];
    const float* b2    = (const float*)d_in[6];
    const int*   m_idx = (const int*)d_in[7];
    const int*   n_idx = (const int*)d_in[8];
    float* out = (float*)d_out;

    int S = in_sizes[7];
    int B = in_sizes[0] / (41 * 2 * 2);

    char* ws = (char*)d_ws;
    unsigned short* Wp  = (unsigned short*)(ws + WP_OFF);
    unsigned short* W2p = (unsigned short*)(ws + W2P_OFF);

    int prep_n = KS1 * 2 * 64 * 2 + KS2 * 2 * 64 * 2;   // 31744
    prep_kernel<<<(prep_n + 255) / 256, 256, 0, stream>>>(W1, W2, pbcC, Wp, W2p, S);

    int grid = (B + NCOL - 1) / NCOL;
    eqsonn_kernel<<<grid, 512, 0, stream>>>(x, task, Wp, W2p, m_idx, n_idx,
                                            b1, b2, out, B, S);
}

// Round 4
// 90.100 us; speedup vs baseline: 1.6542x; 1.6542x over previous
//
#include <hip/hip_runtime.h>
#include <hip/hip_bf16.h>

typedef short bf16x8 __attribute__((ext_vector_type(8)));
typedef float f32x16 __attribute__((ext_vector_type(16)));
typedef float f32x4  __attribute__((ext_vector_type(4)));
typedef float f32x2  __attribute__((ext_vector_type(2)));

#define NCOL  32
#define KS1   112             // f1 k-steps (K=1792, 16 per step, 4 s per step)
#define KS2   12              // f2 k-steps (K=192)
#define ESTR  528             // E row stride bytes (32 cols * 16B + 16 pad)

#define WP_OFF   0            // short [112][2][64][8] = 229376 B
#define W2P_OFF  229376       // short [12][2][64][8]  = 24576 B

#define MET_OFF  21648        // E region 41*528 = 21648; meta uint2[464] = 3712
#define SUM_OFF  25360        // f32 [88][32] = 11264 (waves 0-3)
#define SUM2_OFF 36624        // f32 [88][32] = 11264 (waves 4-7)
#define LDS_BYTES 47888

__device__ __forceinline__ unsigned short f2bf(float f) {
    union { float f; unsigned u; } v; v.f = f;
    unsigned r = v.u + 0x7FFFu + ((v.u >> 16) & 1u);
    return (unsigned short)(r >> 16);
}
__device__ __forceinline__ unsigned pk2(float a, float b) {
    __hip_bfloat162 h = __float22bfloat162_rn(make_float2(a, b));
    unsigned u; __builtin_memcpy(&u, &h, 4); return u;
}
__device__ __forceinline__ bf16x8 asbf(uint4 v) {
    union { uint4 u; bf16x8 b; } z; z.u = v; return z.b;
}
__device__ __forceinline__ f32x16 zero16() {
    f32x16 z;
#pragma unroll
    for (int i = 0; i < 16; ++i) z[i] = 0.f;
    return z;
}

// prep: A-frag layout for mfma_32x32x16 (validated mapping from prior session).
// Wp[ks][mt][lane][8 shorts]; row = mt*32 + (lane&31); k = ks*16+(lane>>5)*8+v.
// Rows 0..39 = W1 (o=row>>2, p=(row>>1)&1, reim=row&1); rows 40..43 = pbc C;
// rows 44..63 zero.
// k -> s=k>>2, t=k&3 (i=t&1 pol, cc=t>>1 re/im), plane j=i^p.
__global__ void prep_kernel(const float* __restrict__ W1,
                            const float* __restrict__ W2,
                            const float* __restrict__ pbcC,
                            unsigned short* __restrict__ Wp,
                            unsigned short* __restrict__ W2p, int S) {
    int idx = blockIdx.x * 256 + threadIdx.x;
    const int N1 = KS1 * 2 * 64 * 2;   // 28672
    const int N2 = KS2 * 2 * 64 * 2;   // 3072
    if (idx < N1) {
        int ks = idx >> 8, rem = idx & 255;
        int mt = rem >> 7; rem &= 127;
        int lane = rem >> 1, jh = rem & 1;
        int row = mt * 32 + (lane & 31);
        int kg  = ks * 16 + (lane >> 5) * 8 + jh * 4;
        int s   = kg >> 2;
        float2 wj0 = make_float2(0.f, 0.f), wj1 = make_float2(0.f, 0.f);
        int p = 0, r = 0;
        if (s < S) {
            if (row < 40) {
                int o = row >> 2; p = (row >> 1) & 1; r = row & 1;
                wj0 = ((const float2*)W1)[(size_t)(o * 2 + 0) * S + s];
                wj1 = ((const float2*)W1)[(size_t)(o * 2 + 1) * S + s];
            } else if (row < 44) {
                p = (row >> 1) & 1; r = row & 1;
                wj0 = ((const float2*)pbcC)[s];
            }
        }
        ushort4 h; unsigned short us[4];
#pragma unroll
        for (int t = 0; t < 4; ++t) {
            int i = t & 1, cc = t >> 1, j2 = i ^ p;
            float2 w = j2 ? wj1 : wj0;
            float v = (cc == 0) ? (r ? w.y : w.x) : (r ? w.x : -w.y);
            us[t] = f2bf(v);
        }
        h.x = us[0]; h.y = us[1]; h.z = us[2]; h.w = us[3];
        ((ushort4*)Wp)[idx] = h;
        return;
    }
    idx -= N1;
    if (idx < N2) {
        int ks = idx >> 8, rem = idx & 255;
        int mt = rem >> 7; rem &= 127;
        int lane = rem >> 1, jh = rem & 1;
        int row = mt * 32 + (lane & 31);
        int kg  = ks * 16 + (lane >> 5) * 8 + jh * 4;
        int m   = kg >> 2;
        float2 wj0 = make_float2(0.f, 0.f), wj1 = make_float2(0.f, 0.f);
        int p = 0, r = 0;
        if (m < 41 && row < 40) {
            int o = row >> 2; p = (row >> 1) & 1; r = row & 1;
            wj0 = ((const float2*)W2)[(o * 2 + 0) * 41 + m];
            wj1 = ((const float2*)W2)[(o * 2 + 1) * 41 + m];
        }
        ushort4 h; unsigned short us[4];
#pragma unroll
        for (int t = 0; t < 4; ++t) {
            int i = t & 1, cc = t >> 1, j2 = i ^ p;
            float2 w = j2 ? wj1 : wj0;
            float v = (cc == 0) ? (r ? w.y : w.x) : (r ? w.x : -w.y);
            us[t] = f2bf(v);
        }
        h.x = us[0]; h.y = us[1]; h.z = us[2]; h.w = us[3];
        ((ushort4*)W2p)[idx] = h;
    }
}

// 512-thr blocks: 32 cols, 8 waves = K-eighths (14 ks each) -> 4 waves/SIMD.
// E staged in LDS as fp32, re/im-split packed (r0,r1,i0,i1); complex math as
// packed f32x2 (v_pk_fma). A-frags prefetched 2 ks ahead (L2 latency cover).
// Reduction: phased plain-LDS dumps (NO fp atomics -- hipcc lowers LDS fp32
// atomicAdd to a CAS loop without -munsafe-fp-atomics; measured 8x slowdown).
// Compact Sum layout: f1 rows 0..47, f2 rows 48..87 -> 11 KB/region,
// 47888 B total LDS -> 3 blocks/CU co-residency.
__global__ __launch_bounds__(512, 4) void eqsonn_kernel(
    const float* __restrict__ x, const float* __restrict__ task,
    const unsigned short* __restrict__ Wp,  // short [112][2][64][8]
    const unsigned short* __restrict__ W2p, // short [12][2][64][8]
    const int* __restrict__ m_idx, const int* __restrict__ n_idx,
    const float* __restrict__ b1, const float* __restrict__ b2,
    float* __restrict__ out, int B, int S)
{
    __shared__ alignas(16) char ldsb[LDS_BYTES];
    const int tid  = threadIdx.x;
    const int lane = tid & 63;
    const int w    = __builtin_amdgcn_readfirstlane(tid >> 6);   // 0..7
    const int col  = lane & 31;
    const int kha  = lane >> 5;
    const int b0   = blockIdx.x * NCOL;

    // ---- stage E fp32: row k at k*528 + col*16, permuted to (r0,r1,i0,i1) ----
    for (int e = tid; e < 41 * NCOL; e += 512) {
        int bb = e / 41, k = e - bb * 41;
        int bs = b0 + bb; if (bs > B - 1) bs = B - 1;
        float4 v = ((const float4*)x)[(size_t)bs * 41 + k];
        f32x4 pv; pv.x = v.x; pv.y = v.z; pv.z = v.y; pv.w = v.w;
        *(f32x4*)(ldsb + k * ESTR + bb * 16) = pv;
    }
    // ---- stage meta byte-offsets, zero-padded to 464 ----
    if (tid < 464) {
        int m = 0, n = 0;
        if (tid < S) { m = m_idx[tid]; n = n_idx[tid]; }
        unsigned offM = (unsigned)((20 + m) * ESTR);
        unsigned offB = (unsigned)((20 + m + n) * ESTR);
        unsigned offN = (unsigned)((20 + n) * ESTR);
        *(uint2*)(ldsb + MET_OFF + tid * 8) = make_uint2(offM | (offB << 16), offN);
    }
    __syncthreads();

    const char* Ebase = ldsb + col * 16;
    auto ldM4 = [&](int ks) -> uint4 {
        return *(const uint4*)(ldsb + MET_OFF + (ks * 4 + kha * 2) * 8);
    };
    auto ldE = [&](unsigned off) -> f32x4 {
        return *(const f32x4*)(Ebase + off);
    };
    // em/eq/en = (r0, r1, i0, i1); A = sum_p E_m[p]*conj(E_q[p]); F[p]=A*E_n[p]
    auto fbuild = [&](f32x4 em, f32x4 eq, f32x4 en, unsigned& lo, unsigned& hi) {
        f32x2 mr = em.xy, mi = em.zw;
        f32x2 qr = eq.xy, qi = eq.zw;
        f32x2 nr = en.xy, ni = en.zw;
        f32x2 t = mr * qr + mi * qi;       // Re per-pol
        f32x2 u = mi * qr - mr * qi;       // Im per-pol
        float sr = t.x + t.y, si = u.x + u.y;
        f32x2 Fr = sr * nr - si * ni;
        f32x2 Fi = sr * ni + si * nr;
        lo = pk2(Fr.x, Fr.y); hi = pk2(Fi.x, Fi.y);
    };

    // ---- f1 K-loop: 14 ksteps/wave, pipelined, barrier-free ----
    f32x16 ac0 = zero16(), ac1 = zero16();
    {
        const int ks0 = w * 14;
        const short* Wp16 = (const short*)Wp;
        uint4 M = ldM4(ks0);
        f32x4 e0 = ldE(M.x & 0xffffu), e1 = ldE(M.x >> 16), e2 = ldE(M.y);
        f32x4 e3 = ldE(M.z & 0xffffu), e4 = ldE(M.z >> 16), e5 = ldE(M.w);
        uint4 Mc = ldM4(ks0 + 1);
        const short* ap0 = Wp16 + (size_t)ks0 * 1024 + lane * 8;
        bf16x8 A0 = *(const bf16x8*)(ap0);
        bf16x8 A1 = *(const bf16x8*)(ap0 + 512);
        const short* ap1 = Wp16 + (size_t)(ks0 + 1) * 1024 + lane * 8;
        bf16x8 B0 = *(const bf16x8*)(ap1);
        bf16x8 B1 = *(const bf16x8*)(ap1 + 512);
        for (int ks = ks0; ks < ks0 + 14; ++ks) {
            // prefetch A-frags 2 ahead (wave-uniform clamp; covers L2 latency)
            int ksn = (ks + 2 < KS1) ? ks + 2 : KS1 - 1;
            const short* apn = Wp16 + (size_t)ksn * 1024 + lane * 8;
            bf16x8 C0 = *(const bf16x8*)(apn);
            bf16x8 C1 = *(const bf16x8*)(apn + 512);
            // prefetch next E values + meta 2 ahead
            f32x4 f0 = ldE(Mc.x & 0xffffu), f1v = ldE(Mc.x >> 16), f2v = ldE(Mc.y);
            f32x4 f3 = ldE(Mc.z & 0xffffu), f4v = ldE(Mc.z >> 16), f5v = ldE(Mc.w);
            uint4 Mn = ldM4(ks + 2);
            unsigned g0, g1, g2, g3;
            fbuild(e0, e1, e2, g0, g1);
            fbuild(e3, e4, e5, g2, g3);
            bf16x8 bfr = asbf(make_uint4(g0, g1, g2, g3));
            ac0 = __builtin_amdgcn_mfma_f32_32x32x16_bf16(A0, bfr, ac0, 0, 0, 0);
            ac1 = __builtin_amdgcn_mfma_f32_32x32x16_bf16(A1, bfr, ac1, 0, 0, 0);
            e0 = f0; e1 = f1v; e2 = f2v; e3 = f3; e4 = f4v; e5 = f5v; Mc = Mn;
            A0 = B0; A1 = B1; B0 = C0; B1 = C1;
        }
    }

    // ---- f2 (E region immutable; m>=41 B-garbage killed by zero A-frags) ----
    f32x16 bc0 = zero16(), bc1 = zero16();
    {
        const short* W216 = (const short*)W2p;
        for (int ks2 = w; ks2 < KS2; ks2 += 8) {
            const short* ap = W216 + (size_t)ks2 * 1024 + lane * 8;
            bf16x8 A0 = *(const bf16x8*)(ap);
            bf16x8 A1 = *(const bf16x8*)(ap + 512);
            unsigned g[4];
#pragma unroll
            for (int j = 0; j < 2; ++j) {
                int m = ks2 * 4 + kha * 2 + j;   // up to 47: rows 41..47 read
                f32x4 v = *(const f32x4*)(ldsb + m * ESTR + col * 16);  // meta pad, finite
                g[j * 2]     = pk2(v.x, v.y);   // (E0r, E1r)
                g[j * 2 + 1] = pk2(v.z, v.w);   // (E0i, E1i)
            }
            bf16x8 bfr = asbf(make_uint4(g[0], g[1], g[2], g[3]));
            bc0 = __builtin_amdgcn_mfma_f32_32x32x16_bf16(A0, bfr, bc0, 0, 0, 0);
            bc1 = __builtin_amdgcn_mfma_f32_32x32x16_bf16(A1, bfr, bc1, 0, 0, 0);
        }
    }

    // ---- phased reduction: waves 0-3 -> Sum, 4-7 -> Sum2; 44 ops/thread ----
    // f1: ac0 rows 0..31 (16 regs), ac1 rows 32..47 (regs 0..7; 8..15 zero).
    // f2: bc0 rows 48..79 (16 regs), bc1 rows 80..87 (regs 0..3; rest zero).
    float* Reg = (float*)(ldsb + ((w < 4) ? SUM_OFF : SUM2_OFF));
    const int ph = w & 3;
    auto dump = [&](f32x16 a, int baserow, int nregs, bool add) {
#pragma unroll
        for (int reg = 0; reg < 16; ++reg) {
            if (reg >= nregs) break;
            int row = baserow + (reg & 3) + 8 * (reg >> 2) + 4 * kha;
            int idx = row * 32 + col;
            if (add) Reg[idx] += a[reg]; else Reg[idx] = a[reg];
        }
    };
    for (int p = 0; p < 4; ++p) {
        if (ph == p) {
            bool add = (p != 0);
            dump(ac0, 0, 16, add); dump(ac1, 32, 8, add);
            dump(bc0, 48, 16, add); dump(bc1, 80, 4, add);
        }
        __syncthreads();
    }

    // ---- merge Sum += Sum2 (704 float4, all 512 threads) ----
    {
        float4* S1 = (float4*)(ldsb + SUM_OFF);
        float4* S2 = (float4*)(ldsb + SUM2_OFF);
#pragma unroll
        for (int i = 0; i < 2; ++i) {
            int idx = tid + i * 512;
            if (idx < 704) {
                float4 a = S1[idx], b = S2[idx];
                a.x += b.x; a.y += b.y; a.z += b.z; a.w += b.w;
                S1[idx] = a;
            }
        }
    }
    __syncthreads();

    // ---- epilogue: wave 0, lanes 0..31 ----
    if (w == 0 && lane < NCOL) {
        const float* Sum = (const float*)(ldsb + SUM_OFF);
        int c = lane;
        float pr0 = Sum[40 * 32 + c], pi0 = Sum[41 * 32 + c];
        float pr1 = Sum[42 * 32 + c], pi1 = Sum[43 * 32 + c];
        float t0 = 0.f, t1 = 0.f, t2 = 0.f, t3 = 0.f;
#pragma unroll
        for (int o = 0; o < 10; ++o) {
            float b2r = b2[o * 2], b2i = b2[o * 2 + 1];
            float b1r = b1[o * 2], b1i = b1[o * 2 + 1];
            int rb = o * 4;
            float B0r = Sum[(48 + rb + 0) * 32 + c] + b2r;
            float B0i = Sum[(48 + rb + 1) * 32 + c] + b2i;
            float B1r = Sum[(48 + rb + 2) * 32 + c] + b2r;
            float B1i = Sum[(48 + rb + 3) * 32 + c] + b2i;
            float A0r = Sum[(rb + 0) * 32 + c] + b1r;
            float A0i = Sum[(rb + 1) * 32 + c] + b1i;
            float A1r = Sum[(rb + 2) * 32 + c] + b1r;
            float A1i = Sum[(rb + 3) * 32 + c] + b1i;
            // A*B*conj(B) + conj(A)*B*B = 2*Re(A*conj(B)) * B
            float g0 = 2.f * (A0r * B0r + A0i * B0i);
            t0 += g0 * B0r; t1 += g0 * B0i;
            float g1 = 2.f * (A1r * B1r + A1i * B1i);
            t2 += g1 * B1r; t3 += g1 * B1i;
        }
        int b = b0 + c;
        if (b < B) {
            float dbm = task[(size_t)b * 4];
            float P   = exp2f(dbm * 0.33219280948873623f) * 0.5f;  // 10^(dbm/10)/2
            float kP2 = 3.1622776601683794e-05f * P * P;           // 1e-4/sqrt(10)*P^2
            float4 Ec = ((const float4*)x)[(size_t)b * 41 + 20];   // fp32 center
            float4 o4;
            o4.x = Ec.x + P * pr0 + kP2 * t0;
            o4.y = Ec.y + P * pi0 + kP2 * t1;
            o4.z = Ec.z + P * pr1 + kP2 * t2;
            o4.w = Ec.w + P * pi1 + kP2 * t3;
            ((float4*)out)[b] = o4;
        }
    }
}

extern "C" void kernel_launch(void* const* d_in, const int* in_sizes, int n_in,
                              void* d_out, int out_size, void* d_ws, size_t ws_size,
                              hipStream_t stream) {
    const float* x     = (const float*)d_in[0];
    const float* task  = (const float*)d_in[1];
    const float* pbcC  = (const float*)d_in[2];
    const float* W1    = (const float*)d_in[3];
    const float* b1    = (const float*)d_in[4];
    const float* W2    = (const float*)d_in[5];
    const float* b2    = (const float*)d_in[6];
    const int*   m_idx = (const int*)d_in[7];
    const int*   n_idx = (const int*)d_in[8];
    float* out = (float*)d_out;

    int S = in_sizes[7];
    int B = in_sizes[0] / (41 * 2 * 2);

    char* ws = (char*)d_ws;
    unsigned short* Wp  = (unsigned short*)(ws + WP_OFF);
    unsigned short* W2p = (unsigned short*)(ws + W2P_OFF);

    int prep_n = KS1 * 2 * 64 * 2 + KS2 * 2 * 64 * 2;   // 31744
    prep_kernel<<<(prep_n + 255) / 256, 256, 0, stream>>>(W1, W2, pbcC, Wp, W2p, S);

    int grid = (B + NCOL - 1) / NCOL;
    eqsonn_kernel<<<grid, 512, 0, stream>>>(x, task, Wp, W2p, m_idx, n_idx,
                                            b1, b2, out, B, S);
}